// Round 12
// baseline (168.118 us; speedup 1.0000x reference)
//
#include <hip/hip_runtime.h>
#include <hip/hip_bf16.h>

// KAN layer: out = einsum('bik,jik->bj', rbf(x), W) + silu(x)@Wb^T, then LN.
// GEMM view: C[4096,512] = A[4096,8704] * B[512,8704]^T in bf16 MFMA, where
// A = [rbf basis(x) | silu(x)] — fully virtual: basis AND silu computed
// in-GEMM from x. prep is a pure B-cast.
//
// R11 post-mortem: removing the mid-tile s_barrier collapsed the schedule
// (gemm 48.7->71us, MfmaUtil 28->20). That barrier is PACING, not a fence:
// it keeps the 8 waves role-staggered (some MFMA-draining while others
// ds_read). Without it all waves burst 24 ds_reads at once -> convoy.
// R12 = R10's exact 2-phase schedule (mid s_barrier restored) with the ONE
// good R11 change kept: silu in-loop (z=7 tiles: 8 float4 x loads in P0,
// 4 silu8 stores in P1), deleting Asilu + prep's A-part.
//
// d_ws layout (uses 42.5 MB of the 113.7 MB ws):
//   Bm bf16 [512][8704]    @ 0        ( 8,912,896 B)  Bm = [W | Wb]
//   Cp bf16 [8][4096][512] @ 8912896  (33,554,432 B)  split-K partials
//   (B tail over-reads <=128 B past Bm land in Cp: mapped, never consumed)

typedef __bf16 bf16x8 __attribute__((ext_vector_type(8)));
typedef __bf16 bf16x4 __attribute__((ext_vector_type(4)));
typedef float  f32x4  __attribute__((ext_vector_type(4)));

#define KT 8704            // total K = 512*16 + 512
#define SPLITS 8
#define KS (KT / SPLITS)   // 1088 per z-block
#define NT2 (KS / 64)      // 17 K-tiles of BK=64
#define CPE (4096 * 512)   // elements per partial
#define ATILE (256 * 64)   // one tile slot per matrix: 256 rows x 64 k, elems

__device__ __forceinline__ void gll16(const __bf16* g, __bf16* l) {
    __builtin_amdgcn_global_load_lds(
        (const __attribute__((address_space(1))) void*)g,
        (__attribute__((address_space(3))) void*)l, 16, 0, 0);
}

// ---- kernel 1: Bm = [W | Wb] cast to bf16 ---------------------------------
__global__ void prep_B(const float* __restrict__ W, const float* __restrict__ Wb,
                       __bf16* __restrict__ B) {
    int t = blockIdx.x * 256 + threadIdx.x;      // 0 .. 512*2176
    int j = t / 2176;
    int c = (t - j * 2176) * 4;
    float4 v;
    if (c < 8192) v = *(const float4*)&W[(size_t)j * 8192 + c];
    else          v = *(const float4*)&Wb[(size_t)j * 512 + (c - 8192)];
    bf16x4 o;
    o[0] = (__bf16)v.x; o[1] = (__bf16)v.y; o[2] = (__bf16)v.z; o[3] = (__bf16)v.w;
    *(bf16x4*)&B[(size_t)j * KT + c] = o;
}

// ---- kernel 2: fused split-K GEMM, 256x256 tile, 8 waves, BK=64, 2-phase --
// Per K-tile u (= R10 schedule):
//  P0 (ks=0): 12 ds_read | 4 gll16 B(u+1) | if nb: basis stores pt1 (xA,xC)
//     + issue basis x loads (u+2) ; else: 8 float4 silu x loads
//     -> setprio 32 MFMA -> s_barrier   (PACING: role-staggers the waves)
//  P1 (ks=1): 12 ds_read | if nb: basis stores pt2 (xB,xD) ; else: 4 silu8
//     stores -> setprio 32 MFMA -> commit x regs -> __syncthreads
// All staging targets slot^1 (last read in tile u-1, drained by its
// __syncthreads -> WAR-safe). Tile-end __syncthreads publishes A stores
// and drains the B DMA (issued in P0, >=1 phase old).
//
// LDS chunk layout (R9/R10-proven): per slot, 2048 chunks of 16B; chunk g
// holds source (row = g>>3, src col c = (g&7)^((row>>1)&7)). Reads
// de-swizzle with (q or 4+q)^((r16>>1)&7). ALL writes lane-linear:
// thread t -> chunks t,512+t,1024+t,1536+t (zero-conflict, R9-measured).
__global__ __launch_bounds__(512, 2) void gemm_bt(const float* __restrict__ xg,
                                                  const __bf16* __restrict__ B,
                                                  __bf16* __restrict__ Cp) {
    __shared__ __attribute__((aligned(16))) __bf16 As[2 * ATILE];
    __shared__ __attribute__((aligned(16))) __bf16 Bs[2 * ATILE];

    const int tid  = threadIdx.x;
    const int wave = tid >> 6, lane = tid & 63;
    const int q    = lane >> 4, r16 = lane & 15;
    const int m0 = blockIdx.x * 256, n0 = blockIdx.y * 256, k0 = blockIdx.z * KS;
    const int wm = wave >> 2, wn = wave & 3;     // 2x4 waves; per-wave 128x64 out

    const int sr = tid >> 3;                           // 0..63
    const int sc = (tid & 7) ^ ((tid >> 4) & 7);       // de-swizzled source col
    const __bf16* gB0 = B + (size_t)(n0 + sr) * KT       + k0 + sc * 8;
    const __bf16* gB1 = B + (size_t)(n0 + 64  + sr) * KT + k0 + sc * 8;
    const __bf16* gB2 = B + (size_t)(n0 + 128 + sr) * KT + k0 + sc * 8;
    const __bf16* gB3 = B + (size_t)(n0 + 192 + sr) * KT + k0 + sc * 8;
    // x row bases (f32): rows sr, sr+64, sr+128, sr+192 of this m-tile
    const float* xs0 = xg + (size_t)(m0 + sr) * 512;
    const float* xs1 = xg + (size_t)(m0 + 64  + sr) * 512;
    const float* xs2 = xg + (size_t)(m0 + 128 + sr) * 512;
    const float* xs3 = xg + (size_t)(m0 + 192 + sr) * 512;
    // basis x col: (kbase>>4) + (sc>>1); j-half = 8*(sc&1)
    const int   xco = sc >> 1;
    const float j0f = (float)(8 * (sc & 1));

    f32x4 acc[8][4] = {};

    // read offsets (XOR de-swizzle, = R9/R10)
    const int swl = (r16 >> 1) & 7;
    const int qx0 = ((q)     ^ swl) * 8;         // ks=0 chunk
    const int qx1 = ((4 + q) ^ swl) * 8;         // ks=1 chunk
    const int aro = (wm * 128 + r16) * 64;
    const int bro = (wn * 64  + r16) * 64;

    // 8 basis values (j = j0..j0+7) for one x value
    auto basis8 = [&](float xv) -> bf16x8 {
        const float zc = 3.75f * xv + 7.5f - j0f;    // z_j = zc - d
        bf16x8 o;
#pragma unroll
        for (int d = 0; d < 8; ++d) { float z = zc - (float)d; o[d] = (__bf16)__expf(-z * z); }
        return o;
    };
    // 8 silu values from two float4
    auto silu8 = [&](float4 va, float4 vb) -> bf16x8 {
        float v[8] = {va.x, va.y, va.z, va.w, vb.x, vb.y, vb.z, vb.w};
        bf16x8 o;
#pragma unroll
        for (int d = 0; d < 8; ++d) o[d] = (__bf16)(v[d] / (1.0f + __expf(-v[d])));
        return o;
    };

    // prologue: B(0) via gll16 (gB* already at k0); A(0) basis (tile 0 is
    // basis for all z: max k0 = 7616 < 8192), lane-linear stores into slot 0.
    // Pre-load x scalars for tile 0's basis staging (tile 1 at (k0+64)>>4).
    float xA, xB, xC, xD;
    {
        const int xo = (k0 >> 4) + xco;
        float x0 = xs0[xo], x1 = xs1[xo], x2 = xs2[xo], x3 = xs3[xo];
        gll16(gB0, &Bs[(size_t)tid * 8]);
        gll16(gB1, &Bs[(size_t)(512 + tid) * 8]);
        gll16(gB2, &Bs[(size_t)(1024 + tid) * 8]);
        gll16(gB3, &Bs[(size_t)(1536 + tid) * 8]);
        *(bf16x8*)(As + (size_t)tid * 8)          = basis8(x0);
        *(bf16x8*)(As + (size_t)(512 + tid) * 8)  = basis8(x1);
        *(bf16x8*)(As + (size_t)(1024 + tid) * 8) = basis8(x2);
        *(bf16x8*)(As + (size_t)(1536 + tid) * 8) = basis8(x3);
        const int xo1 = ((k0 + 64) >> 4) + xco;  // always < 512 (k0 max 7616)
        xA = xs0[xo1]; xB = xs1[xo1]; xC = xs2[xo1]; xD = xs3[xo1];
    }
    __syncthreads();

    bf16x8 a[8], b[4];
    for (int u = 0; u < NT2; ++u) {
        const int s   = u & 1;
        const int cbo = s * ATILE;               // compute slot (tile u)
        const int so1 = (s ^ 1) * ATILE;         // staging slot (tile u+1)
        const int k1  = (u + 1) * 64;            // tile-local (gB*: k0 baked in)
        const int kn  = k0 + k1;                 // GLOBAL k-base of tile u+1
        const bool nb = kn < 8192;               // tile u+1 is basis?
        // silu col base, clamped for the never-consumed tail stage (x is an
        // INPUT buffer — no over-read allowed): kk<=448 keeps cols <=511.
        const int kk  = (kn - 8192 > 448) ? 448 : (kn - 8192);
        const int k2g = kn + 64;                 // GLOBAL k-base of tile u+2
        const bool nb2 = k2g < 8192;             // tile u+2 is basis?
        float t0, t1, t2, t3;                    // basis x loads for tile u+2
        float4 sa0, sa1, sb0, sb1, sc0, sc1, sd0, sd1;   // silu x (tile u+1)

        // ======== P0: ks=0 (12 ds_read, all DMA + x loads, 32 MFMA) ========
#pragma unroll
        for (int mi = 0; mi < 8; ++mi) a[mi] = *(const bf16x8*)(As + cbo + aro + mi * 1024 + qx0);
#pragma unroll
        for (int ni = 0; ni < 4; ++ni) b[ni] = *(const bf16x8*)(Bs + cbo + bro + ni * 1024 + qx0);
        gll16(gB0 + k1, &Bs[(size_t)(so1 + tid * 8)]);
        gll16(gB1 + k1, &Bs[(size_t)(so1 + (512 + tid) * 8)]);
        gll16(gB2 + k1, &Bs[(size_t)(so1 + (1024 + tid) * 8)]);
        gll16(gB3 + k1, &Bs[(size_t)(so1 + (1536 + tid) * 8)]);
        if (nb) {                                // basis stores pt1 (x from last tile)
            *(bf16x8*)(As + so1 + (size_t)tid * 8)          = basis8(xA);
            *(bf16x8*)(As + so1 + (size_t)(1024 + tid) * 8) = basis8(xC);
        } else {                                 // silu x loads (z=7 only)
            const int col = kk + sc * 8;
            sa0 = *(const float4*)(xs0 + col); sa1 = *(const float4*)(xs0 + col + 4);
            sb0 = *(const float4*)(xs1 + col); sb1 = *(const float4*)(xs1 + col + 4);
            sc0 = *(const float4*)(xs2 + col); sc1 = *(const float4*)(xs2 + col + 4);
            sd0 = *(const float4*)(xs3 + col); sd1 = *(const float4*)(xs3 + col + 4);
        }
        if (nb2) {                               // basis x loads for tile u+2
            const int xo = (k2g >> 4) + xco;
            t0 = xs0[xo]; t1 = xs1[xo]; t2 = xs2[xo]; t3 = xs3[xo];
        }
        __builtin_amdgcn_s_setprio(1);
#pragma unroll
        for (int mi = 0; mi < 8; ++mi)
#pragma unroll
            for (int ni = 0; ni < 4; ++ni)
                acc[mi][ni] = __builtin_amdgcn_mfma_f32_16x16x32_bf16(a[mi], b[ni], acc[mi][ni], 0, 0, 0);
        __builtin_amdgcn_s_setprio(0);
        __builtin_amdgcn_s_barrier();            // PACING barrier (load-bearing)

        // ======== P1: ks=1 (12 ds_read, A stores, 32 MFMA) ========
#pragma unroll
        for (int mi = 0; mi < 8; ++mi) a[mi] = *(const bf16x8*)(As + cbo + aro + mi * 1024 + qx1);
#pragma unroll
        for (int ni = 0; ni < 4; ++ni) b[ni] = *(const bf16x8*)(Bs + cbo + bro + ni * 1024 + qx1);
        if (nb) {                                // basis stores pt2
            *(bf16x8*)(As + so1 + (size_t)(512 + tid) * 8)  = basis8(xB);
            *(bf16x8*)(As + so1 + (size_t)(1536 + tid) * 8) = basis8(xD);
        } else {                                 // silu stores (z=7)
            *(bf16x8*)(As + so1 + (size_t)tid * 8)          = silu8(sa0, sa1);
            *(bf16x8*)(As + so1 + (size_t)(512 + tid) * 8)  = silu8(sb0, sb1);
            *(bf16x8*)(As + so1 + (size_t)(1024 + tid) * 8) = silu8(sc0, sc1);
            *(bf16x8*)(As + so1 + (size_t)(1536 + tid) * 8) = silu8(sd0, sd1);
        }
        __builtin_amdgcn_s_setprio(1);
#pragma unroll
        for (int mi = 0; mi < 8; ++mi)
#pragma unroll
            for (int ni = 0; ni < 4; ++ni)
                acc[mi][ni] = __builtin_amdgcn_mfma_f32_16x16x32_bf16(a[mi], b[ni], acc[mi][ni], 0, 0, 0);
        __builtin_amdgcn_s_setprio(0);
        if (nb2) { xA = t0; xB = t1; xC = t2; xD = t3; }   // commit for tile u+1
        // tile end: publishes A stores, drains B DMA, recycles slots.
        __syncthreads();
    }

    // epilogue: C/D layout col=lane&15, row=(lane>>4)*4+reg; bf16 partials
    __bf16* Cb = Cp + (size_t)blockIdx.z * CPE;
#pragma unroll
    for (int mi = 0; mi < 8; ++mi) {
        const int row = m0 + wm * 128 + mi * 16 + q * 4;
#pragma unroll
        for (int ni = 0; ni < 4; ++ni) {
            const int col = n0 + wn * 64 + ni * 16 + r16;
#pragma unroll
            for (int r = 0; r < 4; ++r)
                Cb[(size_t)(row + r) * 512 + col] = (__bf16)acc[mi][ni][r];
        }
    }
}

// ---- kernel 3: sum 8 bf16 partials + LayerNorm, one wave per row ----------
__global__ void ln_kernel(const __bf16* __restrict__ Cp, const float* __restrict__ gamma,
                          const float* __restrict__ beta, float* __restrict__ out) {
    const int tid  = threadIdx.x;
    const int wave = tid >> 6, lane = tid & 63;
    const int row  = blockIdx.x * 4 + wave;
    const size_t base = (size_t)row * 512 + lane * 8;   // 8 contiguous cols/lane

    float v[8] = {};
    float s = 0.f, s2 = 0.f;
#pragma unroll
    for (int z = 0; z < SPLITS; ++z) {
        bf16x8 p = *(const bf16x8*)(Cp + (size_t)z * CPE + base);
#pragma unroll
        for (int j = 0; j < 8; ++j) v[j] += (float)p[j];
    }
#pragma unroll
    for (int j = 0; j < 8; ++j) { s += v[j]; s2 += v[j] * v[j]; }
#pragma unroll
    for (int m = 32; m >= 1; m >>= 1) {
        s  += __shfl_xor(s, m);
        s2 += __shfl_xor(s2, m);
    }
    const float mean = s * (1.0f / 512.0f);
    const float var  = s2 * (1.0f / 512.0f) - mean * mean;
    const float rs   = rsqrtf(var + 1e-5f);
    float4 o0, o1;
    const float4 g0 = *(const float4*)&gamma[lane * 8];
    const float4 g1 = *(const float4*)&gamma[lane * 8 + 4];
    const float4 b0 = *(const float4*)&beta[lane * 8];
    const float4 b1 = *(const float4*)&beta[lane * 8 + 4];
    o0.x = (v[0] - mean) * rs * g0.x + b0.x;
    o0.y = (v[1] - mean) * rs * g0.y + b0.y;
    o0.z = (v[2] - mean) * rs * g0.z + b0.z;
    o0.w = (v[3] - mean) * rs * g0.w + b0.w;
    o1.x = (v[4] - mean) * rs * g1.x + b1.x;
    o1.y = (v[5] - mean) * rs * g1.y + b1.y;
    o1.z = (v[6] - mean) * rs * g1.z + b1.z;
    o1.w = (v[7] - mean) * rs * g1.w + b1.w;
    *(float4*)&out[base]     = o0;
    *(float4*)&out[base + 4] = o1;
}

extern "C" void kernel_launch(void* const* d_in, const int* in_sizes, int n_in,
                              void* d_out, int out_size, void* d_ws, size_t ws_size,
                              hipStream_t stream) {
    const float* x     = (const float*)d_in[0];
    const float* W     = (const float*)d_in[1];
    const float* Wb    = (const float*)d_in[2];
    const float* gamma = (const float*)d_in[3];
    const float* beta  = (const float*)d_in[4];
    float* out = (float*)d_out;

    char* ws = (char*)d_ws;
    __bf16* Bm = (__bf16*)ws;                        //  8,912,896 B
    __bf16* Cp = (__bf16*)(ws + 8912896);            // 33,554,432 B

    prep_B<<<4352, 256, 0, stream>>>(W, Wb, Bm);
    dim3 g(16, 2, SPLITS);
    gemm_bt<<<g, 512, 0, stream>>>(x, Bm, Cp);
    ln_kernel<<<1024, 256, 0, stream>>>(Cp, gamma, beta, out);
}

// Round 13
// 144.869 us; speedup vs baseline: 1.1605x; 1.1605x over previous
//
#include <hip/hip_runtime.h>
#include <hip/hip_bf16.h>

// KAN layer: out = einsum('bik,jik->bj', rbf(x), W) + silu(x)@Wb^T, then LN.
// GEMM view: C[4096,512] = A[4096,8704] * B[512,8704]^T in bf16 MFMA, where
// A = [rbf basis(x) | silu(x)] — fully virtual: basis AND silu computed
// in-GEMM from x. prep is a pure B-cast.
//
// R12 post-mortem: WRITE_SIZE 43->68 MB = scratch spills. Mechanism: gfx950
// unified VGPR/AGPR file; acc[8][4] = 128 AGPRs; launch_bounds(512,2) (2
// waves/SIMD) caps the unified budget at 256/wave -> hard VGPR cap 128
// (exactly what the counter reports). R12 held 8 float4 silu regs (32
// VGPRs) ACROSS the mid-tile barrier -> over budget -> per-tile scratch
// save/restore -> MfmaUtil 15.6%. R8 proved 4x bf16x8 (16 regs) crosses a
// barrier spill-free at VGPR 116.
// R13 = R12 with silu loads + exp computation moved into P0 (z=7 branch):
// only the 4 finished bf16x8 results cross the barrier; P1 just stores.
//
// d_ws layout (uses 42.5 MB of the 113.7 MB ws):
//   Bm bf16 [512][8704]    @ 0        ( 8,912,896 B)  Bm = [W | Wb]
//   Cp bf16 [8][4096][512] @ 8912896  (33,554,432 B)  split-K partials
//   (B tail over-reads <=128 B past Bm land in Cp: mapped, never consumed)

typedef __bf16 bf16x8 __attribute__((ext_vector_type(8)));
typedef __bf16 bf16x4 __attribute__((ext_vector_type(4)));
typedef float  f32x4  __attribute__((ext_vector_type(4)));

#define KT 8704            // total K = 512*16 + 512
#define SPLITS 8
#define KS (KT / SPLITS)   // 1088 per z-block
#define NT2 (KS / 64)      // 17 K-tiles of BK=64
#define CPE (4096 * 512)   // elements per partial
#define ATILE (256 * 64)   // one tile slot per matrix: 256 rows x 64 k, elems

__device__ __forceinline__ void gll16(const __bf16* g, __bf16* l) {
    __builtin_amdgcn_global_load_lds(
        (const __attribute__((address_space(1))) void*)g,
        (__attribute__((address_space(3))) void*)l, 16, 0, 0);
}

// ---- kernel 1: Bm = [W | Wb] cast to bf16 ---------------------------------
__global__ void prep_B(const float* __restrict__ W, const float* __restrict__ Wb,
                       __bf16* __restrict__ B) {
    int t = blockIdx.x * 256 + threadIdx.x;      // 0 .. 512*2176
    int j = t / 2176;
    int c = (t - j * 2176) * 4;
    float4 v;
    if (c < 8192) v = *(const float4*)&W[(size_t)j * 8192 + c];
    else          v = *(const float4*)&Wb[(size_t)j * 512 + (c - 8192)];
    bf16x4 o;
    o[0] = (__bf16)v.x; o[1] = (__bf16)v.y; o[2] = (__bf16)v.z; o[3] = (__bf16)v.w;
    *(bf16x4*)&B[(size_t)j * KT + c] = o;
}

// ---- kernel 2: fused split-K GEMM, 256x256 tile, 8 waves, BK=64, 2-phase --
// Per K-tile u (= R10 schedule):
//  P0 (ks=0): 12 ds_read | 4 gll16 B(u+1) | if nb: basis stores pt1 (xA,xC)
//     + issue basis x loads (u+2) ; else: 8 float4 x loads + 4 silu8 COMPUTE
//     -> setprio 32 MFMA -> s_barrier   (PACING: role-staggers the waves)
//  P1 (ks=1): 12 ds_read | if nb: basis stores pt2 (xB,xD) ; else: 4 silu
//     stores (sv0..sv3, 16 VGPRs across the barrier — R8-proven budget)
//     -> setprio 32 MFMA -> commit x regs -> __syncthreads
// All staging targets slot^1 (last read in tile u-1, drained by its
// __syncthreads -> WAR-safe). Tile-end __syncthreads publishes A stores
// and drains the B DMA (issued in P0, >=1 phase old).
//
// LDS chunk layout (R9/R10-proven): per slot, 2048 chunks of 16B; chunk g
// holds source (row = g>>3, src col c = (g&7)^((row>>1)&7)). Reads
// de-swizzle with (q or 4+q)^((r16>>1)&7). ALL writes lane-linear:
// thread t -> chunks t,512+t,1024+t,1536+t (zero-conflict, R9-measured).
__global__ __launch_bounds__(512, 2) void gemm_bt(const float* __restrict__ xg,
                                                  const __bf16* __restrict__ B,
                                                  __bf16* __restrict__ Cp) {
    __shared__ __attribute__((aligned(16))) __bf16 As[2 * ATILE];
    __shared__ __attribute__((aligned(16))) __bf16 Bs[2 * ATILE];

    const int tid  = threadIdx.x;
    const int wave = tid >> 6, lane = tid & 63;
    const int q    = lane >> 4, r16 = lane & 15;
    const int m0 = blockIdx.x * 256, n0 = blockIdx.y * 256, k0 = blockIdx.z * KS;
    const int wm = wave >> 2, wn = wave & 3;     // 2x4 waves; per-wave 128x64 out

    const int sr = tid >> 3;                           // 0..63
    const int sc = (tid & 7) ^ ((tid >> 4) & 7);       // de-swizzled source col
    const __bf16* gB0 = B + (size_t)(n0 + sr) * KT       + k0 + sc * 8;
    const __bf16* gB1 = B + (size_t)(n0 + 64  + sr) * KT + k0 + sc * 8;
    const __bf16* gB2 = B + (size_t)(n0 + 128 + sr) * KT + k0 + sc * 8;
    const __bf16* gB3 = B + (size_t)(n0 + 192 + sr) * KT + k0 + sc * 8;
    // x row bases (f32): rows sr, sr+64, sr+128, sr+192 of this m-tile
    const float* xs0 = xg + (size_t)(m0 + sr) * 512;
    const float* xs1 = xg + (size_t)(m0 + 64  + sr) * 512;
    const float* xs2 = xg + (size_t)(m0 + 128 + sr) * 512;
    const float* xs3 = xg + (size_t)(m0 + 192 + sr) * 512;
    // basis x col: (kbase>>4) + (sc>>1); j-half = 8*(sc&1)
    const int   xco = sc >> 1;
    const float j0f = (float)(8 * (sc & 1));

    f32x4 acc[8][4] = {};

    // read offsets (XOR de-swizzle, = R9/R10)
    const int swl = (r16 >> 1) & 7;
    const int qx0 = ((q)     ^ swl) * 8;         // ks=0 chunk
    const int qx1 = ((4 + q) ^ swl) * 8;         // ks=1 chunk
    const int aro = (wm * 128 + r16) * 64;
    const int bro = (wn * 64  + r16) * 64;

    // 8 basis values (j = j0..j0+7) for one x value
    auto basis8 = [&](float xv) -> bf16x8 {
        const float zc = 3.75f * xv + 7.5f - j0f;    // z_j = zc - d
        bf16x8 o;
#pragma unroll
        for (int d = 0; d < 8; ++d) { float z = zc - (float)d; o[d] = (__bf16)__expf(-z * z); }
        return o;
    };
    // 8 silu values from two float4
    auto silu8 = [&](float4 va, float4 vb) -> bf16x8 {
        float v[8] = {va.x, va.y, va.z, va.w, vb.x, vb.y, vb.z, vb.w};
        bf16x8 o;
#pragma unroll
        for (int d = 0; d < 8; ++d) o[d] = (__bf16)(v[d] / (1.0f + __expf(-v[d])));
        return o;
    };

    // prologue: B(0) via gll16 (gB* already at k0); A(0) basis (tile 0 is
    // basis for all z: max k0 = 7616 < 8192), lane-linear stores into slot 0.
    // Pre-load x scalars for tile 0's basis staging (tile 1 at (k0+64)>>4).
    float xA, xB, xC, xD;
    {
        const int xo = (k0 >> 4) + xco;
        float x0 = xs0[xo], x1 = xs1[xo], x2 = xs2[xo], x3 = xs3[xo];
        gll16(gB0, &Bs[(size_t)tid * 8]);
        gll16(gB1, &Bs[(size_t)(512 + tid) * 8]);
        gll16(gB2, &Bs[(size_t)(1024 + tid) * 8]);
        gll16(gB3, &Bs[(size_t)(1536 + tid) * 8]);
        *(bf16x8*)(As + (size_t)tid * 8)          = basis8(x0);
        *(bf16x8*)(As + (size_t)(512 + tid) * 8)  = basis8(x1);
        *(bf16x8*)(As + (size_t)(1024 + tid) * 8) = basis8(x2);
        *(bf16x8*)(As + (size_t)(1536 + tid) * 8) = basis8(x3);
        const int xo1 = ((k0 + 64) >> 4) + xco;  // always < 512 (k0 max 7616)
        xA = xs0[xo1]; xB = xs1[xo1]; xC = xs2[xo1]; xD = xs3[xo1];
    }
    __syncthreads();

    bf16x8 a[8], b[4];
    for (int u = 0; u < NT2; ++u) {
        const int s   = u & 1;
        const int cbo = s * ATILE;               // compute slot (tile u)
        const int so1 = (s ^ 1) * ATILE;         // staging slot (tile u+1)
        const int k1  = (u + 1) * 64;            // tile-local (gB*: k0 baked in)
        const int kn  = k0 + k1;                 // GLOBAL k-base of tile u+1
        const bool nb = kn < 8192;               // tile u+1 is basis?
        // silu col base, clamped for the never-consumed tail stage (x is an
        // INPUT buffer — no over-read allowed): kk<=448 keeps cols <=511.
        const int kk  = (kn - 8192 > 448) ? 448 : (kn - 8192);
        const int k2g = kn + 64;                 // GLOBAL k-base of tile u+2
        const bool nb2 = k2g < 8192;             // tile u+2 is basis?
        float t0, t1, t2, t3;                    // basis x loads for tile u+2
        bf16x8 sv0, sv1, sv2, sv3;               // finished silu (16 VGPRs)

        // ======== P0: ks=0 (12 ds_read, all DMA + x loads, 32 MFMA) ========
#pragma unroll
        for (int mi = 0; mi < 8; ++mi) a[mi] = *(const bf16x8*)(As + cbo + aro + mi * 1024 + qx0);
#pragma unroll
        for (int ni = 0; ni < 4; ++ni) b[ni] = *(const bf16x8*)(Bs + cbo + bro + ni * 1024 + qx0);
        gll16(gB0 + k1, &Bs[(size_t)(so1 + tid * 8)]);
        gll16(gB1 + k1, &Bs[(size_t)(so1 + (512 + tid) * 8)]);
        gll16(gB2 + k1, &Bs[(size_t)(so1 + (1024 + tid) * 8)]);
        gll16(gB3 + k1, &Bs[(size_t)(so1 + (1536 + tid) * 8)]);
        if (nb) {                                // basis stores pt1 (x from last tile)
            *(bf16x8*)(As + so1 + (size_t)tid * 8)          = basis8(xA);
            *(bf16x8*)(As + so1 + (size_t)(1024 + tid) * 8) = basis8(xC);
        } else {                                 // silu: load + COMPUTE in P0
            const int col = kk + sc * 8;
            sv0 = silu8(*(const float4*)(xs0 + col), *(const float4*)(xs0 + col + 4));
            sv1 = silu8(*(const float4*)(xs1 + col), *(const float4*)(xs1 + col + 4));
            sv2 = silu8(*(const float4*)(xs2 + col), *(const float4*)(xs2 + col + 4));
            sv3 = silu8(*(const float4*)(xs3 + col), *(const float4*)(xs3 + col + 4));
        }
        if (nb2) {                               // basis x loads for tile u+2
            const int xo = (k2g >> 4) + xco;
            t0 = xs0[xo]; t1 = xs1[xo]; t2 = xs2[xo]; t3 = xs3[xo];
        }
        __builtin_amdgcn_s_setprio(1);
#pragma unroll
        for (int mi = 0; mi < 8; ++mi)
#pragma unroll
            for (int ni = 0; ni < 4; ++ni)
                acc[mi][ni] = __builtin_amdgcn_mfma_f32_16x16x32_bf16(a[mi], b[ni], acc[mi][ni], 0, 0, 0);
        __builtin_amdgcn_s_setprio(0);
        __builtin_amdgcn_s_barrier();            // PACING barrier (load-bearing)

        // ======== P1: ks=1 (12 ds_read, A stores, 32 MFMA) ========
#pragma unroll
        for (int mi = 0; mi < 8; ++mi) a[mi] = *(const bf16x8*)(As + cbo + aro + mi * 1024 + qx1);
#pragma unroll
        for (int ni = 0; ni < 4; ++ni) b[ni] = *(const bf16x8*)(Bs + cbo + bro + ni * 1024 + qx1);
        if (nb) {                                // basis stores pt2
            *(bf16x8*)(As + so1 + (size_t)(512 + tid) * 8)  = basis8(xB);
            *(bf16x8*)(As + so1 + (size_t)(1536 + tid) * 8) = basis8(xD);
        } else {                                 // silu stores (z=7)
            *(bf16x8*)(As + so1 + (size_t)tid * 8)          = sv0;
            *(bf16x8*)(As + so1 + (size_t)(512 + tid) * 8)  = sv1;
            *(bf16x8*)(As + so1 + (size_t)(1024 + tid) * 8) = sv2;
            *(bf16x8*)(As + so1 + (size_t)(1536 + tid) * 8) = sv3;
        }
        __builtin_amdgcn_s_setprio(1);
#pragma unroll
        for (int mi = 0; mi < 8; ++mi)
#pragma unroll
            for (int ni = 0; ni < 4; ++ni)
                acc[mi][ni] = __builtin_amdgcn_mfma_f32_16x16x32_bf16(a[mi], b[ni], acc[mi][ni], 0, 0, 0);
        __builtin_amdgcn_s_setprio(0);
        if (nb2) { xA = t0; xB = t1; xC = t2; xD = t3; }   // commit for tile u+1
        // tile end: publishes A stores, drains B DMA, recycles slots.
        __syncthreads();
    }

    // epilogue: C/D layout col=lane&15, row=(lane>>4)*4+reg; bf16 partials
    __bf16* Cb = Cp + (size_t)blockIdx.z * CPE;
#pragma unroll
    for (int mi = 0; mi < 8; ++mi) {
        const int row = m0 + wm * 128 + mi * 16 + q * 4;
#pragma unroll
        for (int ni = 0; ni < 4; ++ni) {
            const int col = n0 + wn * 64 + ni * 16 + r16;
#pragma unroll
            for (int r = 0; r < 4; ++r)
                Cb[(size_t)(row + r) * 512 + col] = (__bf16)acc[mi][ni][r];
        }
    }
}

// ---- kernel 3: sum 8 bf16 partials + LayerNorm, one wave per row ----------
__global__ void ln_kernel(const __bf16* __restrict__ Cp, const float* __restrict__ gamma,
                          const float* __restrict__ beta, float* __restrict__ out) {
    const int tid  = threadIdx.x;
    const int wave = tid >> 6, lane = tid & 63;
    const int row  = blockIdx.x * 4 + wave;
    const size_t base = (size_t)row * 512 + lane * 8;   // 8 contiguous cols/lane

    float v[8] = {};
    float s = 0.f, s2 = 0.f;
#pragma unroll
    for (int z = 0; z < SPLITS; ++z) {
        bf16x8 p = *(const bf16x8*)(Cp + (size_t)z * CPE + base);
#pragma unroll
        for (int j = 0; j < 8; ++j) v[j] += (float)p[j];
    }
#pragma unroll
    for (int j = 0; j < 8; ++j) { s += v[j]; s2 += v[j] * v[j]; }
#pragma unroll
    for (int m = 32; m >= 1; m >>= 1) {
        s  += __shfl_xor(s, m);
        s2 += __shfl_xor(s2, m);
    }
    const float mean = s * (1.0f / 512.0f);
    const float var  = s2 * (1.0f / 512.0f) - mean * mean;
    const float rs   = rsqrtf(var + 1e-5f);
    float4 o0, o1;
    const float4 g0 = *(const float4*)&gamma[lane * 8];
    const float4 g1 = *(const float4*)&gamma[lane * 8 + 4];
    const float4 b0 = *(const float4*)&beta[lane * 8];
    const float4 b1 = *(const float4*)&beta[lane * 8 + 4];
    o0.x = (v[0] - mean) * rs * g0.x + b0.x;
    o0.y = (v[1] - mean) * rs * g0.y + b0.y;
    o0.z = (v[2] - mean) * rs * g0.z + b0.z;
    o0.w = (v[3] - mean) * rs * g0.w + b0.w;
    o1.x = (v[4] - mean) * rs * g1.x + b1.x;
    o1.y = (v[5] - mean) * rs * g1.y + b1.y;
    o1.z = (v[6] - mean) * rs * g1.z + b1.z;
    o1.w = (v[7] - mean) * rs * g1.w + b1.w;
    *(float4*)&out[base]     = o0;
    *(float4*)&out[base + 4] = o1;
}

extern "C" void kernel_launch(void* const* d_in, const int* in_sizes, int n_in,
                              void* d_out, int out_size, void* d_ws, size_t ws_size,
                              hipStream_t stream) {
    const float* x     = (const float*)d_in[0];
    const float* W     = (const float*)d_in[1];
    const float* Wb    = (const float*)d_in[2];
    const float* gamma = (const float*)d_in[3];
    const float* beta  = (const float*)d_in[4];
    float* out = (float*)d_out;

    char* ws = (char*)d_ws;
    __bf16* Bm = (__bf16*)ws;                        //  8,912,896 B
    __bf16* Cp = (__bf16*)(ws + 8912896);            // 33,554,432 B

    prep_B<<<4352, 256, 0, stream>>>(W, Wb, Bm);
    dim3 g(16, 2, SPLITS);
    gemm_bt<<<g, 512, 0, stream>>>(x, Bm, Cp);
    ln_kernel<<<1024, 256, 0, stream>>>(Cp, gamma, beta, out);
}

// Round 14
// 128.758 us; speedup vs baseline: 1.3057x; 1.1251x over previous
//
#include <hip/hip_runtime.h>
#include <hip/hip_bf16.h>

// KAN layer: out = einsum('bik,jik->bj', rbf(x), W) + silu(x)@Wb^T, then LN.
// GEMM view: C[4096,512] = A[4096,8704] * B[512,8704]^T in bf16 MFMA, where
// A = [rbf basis(x) | silu(x)], basis computed in-GEMM (not materialized);
// silu part (4096x512 bf16 = 4.2 MB) pre-materialized and gll16-staged.
//
// R13 post-mortem -> REVERT TO R10 (best measured: 130.4us total, gemm
// 48.7us). The in-loop silu fusion (R11/R12/R13) pinned VGPR at the hard
// 128 cap (= 256 unified regs / 2 waves/SIMD minus acc's 128 AGPRs) and
// squeezed the allocator KERNEL-WIDE — all blocks slowed, though only z=7
// executes the silu branch. R10's 8 regs of slack (VGPR 120) are
// load-bearing. Schedule lessons kept: 2-phase/tile, mid-tile PACING
// s_barrier (R11 showed removing it collapses wave role-stagger),
// lane-linear LDS writes (R9: conflicts 2.2M->0), tile-local k1 for B
// (R5-R7), x prefetched one tile ahead.
//
// d_ws layout (uses 46.7 MB of the 113.7 MB ws):
//   Asilu bf16 [4096][512]   @ 0          ( 4,194,304 B)  silu(x)
//   Bm    bf16 [512][8704]   @ 4194304    ( 8,912,896 B)  Bm = [W | Wb]
//   Cp    bf16 [8][4096][512]@ 13107200   (33,554,432 B)  split-K partials

typedef __bf16 bf16x8 __attribute__((ext_vector_type(8)));
typedef __bf16 bf16x4 __attribute__((ext_vector_type(4)));
typedef float  f32x4  __attribute__((ext_vector_type(4)));

#define KT 8704            // total K = 512*16 + 512
#define SPLITS 8
#define KS (KT / SPLITS)   // 1088 per z-block
#define NT2 (KS / 64)      // 17 K-tiles of BK=64
#define CPE (4096 * 512)   // elements per partial
#define ATILE (256 * 64)   // one tile slot per matrix: 256 rows x 64 k, elems

__device__ __forceinline__ void gll16(const __bf16* g, __bf16* l) {
    __builtin_amdgcn_global_load_lds(
        (const __attribute__((address_space(1))) void*)g,
        (__attribute__((address_space(3))) void*)l, 16, 0, 0);
}

// ---- kernel 1: Asilu = silu(x) (bf16), Bm = [W | Wb] (bf16) ---------------
__global__ void prep_AB(const float* __restrict__ x, const float* __restrict__ W,
                        const float* __restrict__ Wb, __bf16* __restrict__ Asilu,
                        __bf16* __restrict__ B) {
    if (blockIdx.x < 1024) {                     // silu: 8 elems/thread
        int t = blockIdx.x * 256 + threadIdx.x;  // 0 .. 262143
        int e = t * 8;
        float4 v0 = *(const float4*)&x[e];
        float4 v1 = *(const float4*)&x[e + 4];
        float vs[8] = {v0.x, v0.y, v0.z, v0.w, v1.x, v1.y, v1.z, v1.w};
        bf16x8 o;
#pragma unroll
        for (int j = 0; j < 8; ++j) o[j] = (__bf16)(vs[j] / (1.0f + __expf(-vs[j])));
        *(bf16x8*)&Asilu[e] = o;
    } else {                                     // B-part: cast W|Wb, 4 elems/thread
        int t = (blockIdx.x - 1024) * 256 + threadIdx.x;  // 0 .. 512*2176
        int j = t / 2176;
        int c = (t - j * 2176) * 4;
        float4 v;
        if (c < 8192) v = *(const float4*)&W[(size_t)j * 8192 + c];
        else          v = *(const float4*)&Wb[(size_t)j * 512 + (c - 8192)];
        bf16x4 o;
        o[0] = (__bf16)v.x; o[1] = (__bf16)v.y; o[2] = (__bf16)v.z; o[3] = (__bf16)v.w;
        *(bf16x4*)&B[(size_t)j * KT + c] = o;
    }
}

// ---- kernel 2: fused split-K GEMM, 256x256 tile, 8 waves, BK=64, 2-phase --
// Per K-tile u:
//  P0 (ks=0): 12 ds_read (a0-7, b0-3) | 4 gll16 B(u+1) | if nb: 2 basis
//     stores (xA,xC) + issue 4 x loads (tile u+2) ; else 4 silu gll16
//     -> setprio 32 MFMA -> s_barrier   (PACING: role-staggers the waves)
//  P1 (ks=1): 12 ds_read | if nb: 2 basis stores (xB,xD)
//     -> setprio 32 MFMA -> commit x regs -> __syncthreads
// All staging targets slot^1 (last read in tile u-1's P1, drained by its
// __syncthreads -> WAR-safe). Tile-end __syncthreads publishes basis
// ds_writes and drains the DMA (all issued in P0, >=1 phase old).
//
// LDS chunk layout (R9-proven): per slot, 2048 chunks of 16B; chunk g
// holds source (row = g>>3, src col c = (g&7)^((row>>1)&7)). Reads
// de-swizzle with (q or 4+q)^((r16>>1)&7). ALL writes lane-linear:
// thread t -> chunks t,512+t,1024+t,1536+t (zero-conflict, R9-measured).
__global__ __launch_bounds__(512, 2) void gemm_bt(const float* __restrict__ xg,
                                                  const __bf16* __restrict__ Sg,
                                                  const __bf16* __restrict__ B,
                                                  __bf16* __restrict__ Cp) {
    __shared__ __attribute__((aligned(16))) __bf16 As[2 * ATILE];
    __shared__ __attribute__((aligned(16))) __bf16 Bs[2 * ATILE];

    const int tid  = threadIdx.x;
    const int wave = tid >> 6, lane = tid & 63;
    const int q    = lane >> 4, r16 = lane & 15;
    const int m0 = blockIdx.x * 256, n0 = blockIdx.y * 256, k0 = blockIdx.z * KS;
    const int wm = wave >> 2, wn = wave & 3;     // 2x4 waves; per-wave 128x64 out

    const int sr = tid >> 3;                           // 0..63
    const int sc = (tid & 7) ^ ((tid >> 4) & 7);       // de-swizzled source col
    const __bf16* gB0 = B + (size_t)(n0 + sr) * KT       + k0 + sc * 8;
    const __bf16* gB1 = B + (size_t)(n0 + 64  + sr) * KT + k0 + sc * 8;
    const __bf16* gB2 = B + (size_t)(n0 + 128 + sr) * KT + k0 + sc * 8;
    const __bf16* gB3 = B + (size_t)(n0 + 192 + sr) * KT + k0 + sc * 8;
    // silu gll16 source (row stride 512; per-tile kk added later; NO k0)
    const __bf16* gS0 = Sg + (size_t)(m0 + sr) * 512       + sc * 8;
    const __bf16* gS1 = Sg + (size_t)(m0 + 64  + sr) * 512 + sc * 8;
    const __bf16* gS2 = Sg + (size_t)(m0 + 128 + sr) * 512 + sc * 8;
    const __bf16* gS3 = Sg + (size_t)(m0 + 192 + sr) * 512 + sc * 8;
    // basis x sources: thread t needs x[m0 + sr + {0,64,128,192}][xcol],
    // xcol = (kbase>>4) + (sc>>1); j-half = 8*(sc&1).
    const float* xp0 = xg + (size_t)(m0 + sr) * 512       + (sc >> 1);
    const float* xp1 = xg + (size_t)(m0 + 64  + sr) * 512 + (sc >> 1);
    const float* xp2 = xg + (size_t)(m0 + 128 + sr) * 512 + (sc >> 1);
    const float* xp3 = xg + (size_t)(m0 + 192 + sr) * 512 + (sc >> 1);
    const float j0f  = (float)(8 * (sc & 1));

    f32x4 acc[8][4] = {};

    // read offsets (XOR de-swizzle, = R9)
    const int swl = (r16 >> 1) & 7;
    const int qx0 = ((q)     ^ swl) * 8;         // ks=0 chunk
    const int qx1 = ((4 + q) ^ swl) * 8;         // ks=1 chunk
    const int aro = (wm * 128 + r16) * 64;
    const int bro = (wn * 64  + r16) * 64;

    // 8 basis values (j = j0..j0+7) for one x value
    auto basis8 = [&](float xv) -> bf16x8 {
        const float zc = 3.75f * xv + 7.5f - j0f;    // z_j = zc - d
        bf16x8 o;
#pragma unroll
        for (int d = 0; d < 8; ++d) { float z = zc - (float)d; o[d] = (__bf16)__expf(-z * z); }
        return o;
    };

    // prologue: B(0) via gll16 (gB* already at k0); A(0) basis (tile 0 is
    // basis for all z: max k0 = 7616 < 8192), lane-linear stores into slot 0.
    // Pre-load x scalars for tile 0's basis staging (tile 1 at (k0+64)>>4).
    float xA, xB, xC, xD;
    {
        const int xo = k0 >> 4;
        float x0 = xp0[xo], x1 = xp1[xo], x2 = xp2[xo], x3 = xp3[xo];
        gll16(gB0, &Bs[(size_t)tid * 8]);
        gll16(gB1, &Bs[(size_t)(512 + tid) * 8]);
        gll16(gB2, &Bs[(size_t)(1024 + tid) * 8]);
        gll16(gB3, &Bs[(size_t)(1536 + tid) * 8]);
        *(bf16x8*)(As + (size_t)tid * 8)          = basis8(x0);
        *(bf16x8*)(As + (size_t)(512 + tid) * 8)  = basis8(x1);
        *(bf16x8*)(As + (size_t)(1024 + tid) * 8) = basis8(x2);
        *(bf16x8*)(As + (size_t)(1536 + tid) * 8) = basis8(x3);
        const int xo1 = (k0 + 64) >> 4;          // always < 512 (k0 max 7616)
        xA = xp0[xo1]; xB = xp1[xo1]; xC = xp2[xo1]; xD = xp3[xo1];
    }
    __syncthreads();

    bf16x8 a[8], b[4];
    for (int u = 0; u < NT2; ++u) {
        const int s   = u & 1;
        const int cbo = s * ATILE;               // compute slot (tile u)
        const int so1 = (s ^ 1) * ATILE;         // staging slot (tile u+1)
        const int k1  = (u + 1) * 64;            // tile-local (gB*: k0 baked in)
        const int kn  = k0 + k1;                 // GLOBAL k-base of tile u+1
        const bool nb = kn < 8192;               // tile u+1 is basis?
        const int kk  = kn - 8192;               // silu col base (when !nb)
        const int k2g = kn + 64;                 // GLOBAL k-base of tile u+2
        const bool nb2 = k2g < 8192;             // tile u+2 is basis?
        float t0, t1, t2, t3;                    // x loads for tile u+2
        // Tail (u+1==NT2): basis z<7 writes a never-consumed tile from valid
        // x cols (<=480); silu z=7 reads <=512 elems past Asilu rows ->
        // lands in Bm (mapped, unused); B reads <=128 B past the slice ->
        // mapped, never consumed.

        // ======== P0: ks=0 (12 ds_read, all DMA, 32 MFMA) ========
#pragma unroll
        for (int mi = 0; mi < 8; ++mi) a[mi] = *(const bf16x8*)(As + cbo + aro + mi * 1024 + qx0);
#pragma unroll
        for (int ni = 0; ni < 4; ++ni) b[ni] = *(const bf16x8*)(Bs + cbo + bro + ni * 1024 + qx0);
        gll16(gB0 + k1, &Bs[(size_t)(so1 + tid * 8)]);
        gll16(gB1 + k1, &Bs[(size_t)(so1 + (512 + tid) * 8)]);
        gll16(gB2 + k1, &Bs[(size_t)(so1 + (1024 + tid) * 8)]);
        gll16(gB3 + k1, &Bs[(size_t)(so1 + (1536 + tid) * 8)]);
        if (nb) {                                // basis stores pt1 (x from last tile)
            *(bf16x8*)(As + so1 + (size_t)tid * 8)          = basis8(xA);
            *(bf16x8*)(As + so1 + (size_t)(1024 + tid) * 8) = basis8(xC);
        } else {                                 // silu DMA (z=7)
            gll16(gS0 + kk, &As[(size_t)(so1 + tid * 8)]);
            gll16(gS1 + kk, &As[(size_t)(so1 + (512 + tid) * 8)]);
            gll16(gS2 + kk, &As[(size_t)(so1 + (1024 + tid) * 8)]);
            gll16(gS3 + kk, &As[(size_t)(so1 + (1536 + tid) * 8)]);
        }
        if (nb2) {                               // issue x loads for tile u+2
            const int xo = k2g >> 4;
            t0 = xp0[xo]; t1 = xp1[xo]; t2 = xp2[xo]; t3 = xp3[xo];
        }
        __builtin_amdgcn_s_setprio(1);
#pragma unroll
        for (int mi = 0; mi < 8; ++mi)
#pragma unroll
            for (int ni = 0; ni < 4; ++ni)
                acc[mi][ni] = __builtin_amdgcn_mfma_f32_16x16x32_bf16(a[mi], b[ni], acc[mi][ni], 0, 0, 0);
        __builtin_amdgcn_s_setprio(0);
        __builtin_amdgcn_s_barrier();            // PACING barrier (load-bearing)

        // ======== P1: ks=1 (12 ds_read, basis pt2, 32 MFMA) ========
#pragma unroll
        for (int mi = 0; mi < 8; ++mi) a[mi] = *(const bf16x8*)(As + cbo + aro + mi * 1024 + qx1);
#pragma unroll
        for (int ni = 0; ni < 4; ++ni) b[ni] = *(const bf16x8*)(Bs + cbo + bro + ni * 1024 + qx1);
        if (nb) {                                // basis stores pt2
            *(bf16x8*)(As + so1 + (size_t)(512 + tid) * 8)  = basis8(xB);
            *(bf16x8*)(As + so1 + (size_t)(1536 + tid) * 8) = basis8(xD);
        }
        __builtin_amdgcn_s_setprio(1);
#pragma unroll
        for (int mi = 0; mi < 8; ++mi)
#pragma unroll
            for (int ni = 0; ni < 4; ++ni)
                acc[mi][ni] = __builtin_amdgcn_mfma_f32_16x16x32_bf16(a[mi], b[ni], acc[mi][ni], 0, 0, 0);
        __builtin_amdgcn_s_setprio(0);
        if (nb2) { xA = t0; xB = t1; xC = t2; xD = t3; }   // commit for tile u+1
        // tile end: publishes basis ds_writes, drains DMA, recycles slots.
        __syncthreads();
    }

    // epilogue: C/D layout col=lane&15, row=(lane>>4)*4+reg; bf16 partials
    __bf16* Cb = Cp + (size_t)blockIdx.z * CPE;
#pragma unroll
    for (int mi = 0; mi < 8; ++mi) {
        const int row = m0 + wm * 128 + mi * 16 + q * 4;
#pragma unroll
        for (int ni = 0; ni < 4; ++ni) {
            const int col = n0 + wn * 64 + ni * 16 + r16;
#pragma unroll
            for (int r = 0; r < 4; ++r)
                Cb[(size_t)(row + r) * 512 + col] = (__bf16)acc[mi][ni][r];
        }
    }
}

// ---- kernel 3: sum 8 bf16 partials + LayerNorm, one wave per row ----------
__global__ void ln_kernel(const __bf16* __restrict__ Cp, const float* __restrict__ gamma,
                          const float* __restrict__ beta, float* __restrict__ out) {
    const int tid  = threadIdx.x;
    const int wave = tid >> 6, lane = tid & 63;
    const int row  = blockIdx.x * 4 + wave;
    const size_t base = (size_t)row * 512 + lane * 8;   // 8 contiguous cols/lane

    float v[8] = {};
    float s = 0.f, s2 = 0.f;
#pragma unroll
    for (int z = 0; z < SPLITS; ++z) {
        bf16x8 p = *(const bf16x8*)(Cp + (size_t)z * CPE + base);
#pragma unroll
        for (int j = 0; j < 8; ++j) v[j] += (float)p[j];
    }
#pragma unroll
    for (int j = 0; j < 8; ++j) { s += v[j]; s2 += v[j] * v[j]; }
#pragma unroll
    for (int m = 32; m >= 1; m >>= 1) {
        s  += __shfl_xor(s, m);
        s2 += __shfl_xor(s2, m);
    }
    const float mean = s * (1.0f / 512.0f);
    const float var  = s2 * (1.0f / 512.0f) - mean * mean;
    const float rs   = rsqrtf(var + 1e-5f);
    float4 o0, o1;
    const float4 g0 = *(const float4*)&gamma[lane * 8];
    const float4 g1 = *(const float4*)&gamma[lane * 8 + 4];
    const float4 b0 = *(const float4*)&beta[lane * 8];
    const float4 b1 = *(const float4*)&beta[lane * 8 + 4];
    o0.x = (v[0] - mean) * rs * g0.x + b0.x;
    o0.y = (v[1] - mean) * rs * g0.y + b0.y;
    o0.z = (v[2] - mean) * rs * g0.z + b0.z;
    o0.w = (v[3] - mean) * rs * g0.w + b0.w;
    o1.x = (v[4] - mean) * rs * g1.x + b1.x;
    o1.y = (v[5] - mean) * rs * g1.y + b1.y;
    o1.z = (v[6] - mean) * rs * g1.z + b1.z;
    o1.w = (v[7] - mean) * rs * g1.w + b1.w;
    *(float4*)&out[base]     = o0;
    *(float4*)&out[base + 4] = o1;
}

extern "C" void kernel_launch(void* const* d_in, const int* in_sizes, int n_in,
                              void* d_out, int out_size, void* d_ws, size_t ws_size,
                              hipStream_t stream) {
    const float* x     = (const float*)d_in[0];
    const float* W     = (const float*)d_in[1];
    const float* Wb    = (const float*)d_in[2];
    const float* gamma = (const float*)d_in[3];
    const float* beta  = (const float*)d_in[4];
    float* out = (float*)d_out;

    char* ws = (char*)d_ws;
    __bf16* Asilu = (__bf16*)ws;                     //  4,194,304 B
    __bf16* Bm    = (__bf16*)(ws + 4194304);         //  8,912,896 B
    __bf16* Cp    = (__bf16*)(ws + 13107200);        // 33,554,432 B

    prep_AB<<<1024 + 4352, 256, 0, stream>>>(x, W, Wb, Asilu, Bm);
    dim3 g(16, 2, SPLITS);
    gemm_bt<<<g, 512, 0, stream>>>(x, Asilu, Bm, Cp);
    ln_kernel<<<1024, 256, 0, stream>>>(Cp, gamma, beta, out);
}

// Round 16
// 128.100 us; speedup vs baseline: 1.3124x; 1.0051x over previous
//
#include <hip/hip_runtime.h>
#include <hip/hip_bf16.h>

// KAN layer: out = einsum('bik,jik->bj', rbf(x), W) + silu(x)@Wb^T, then LN.
// GEMM view: C[4096,512] = A[4096,8704] * B[512,8704]^T in bf16 MFMA, where
// A = [rbf basis(x) | silu(x)], basis computed in-GEMM (not materialized);
// silu part (4096x512 bf16 = 4.2 MB) pre-materialized and gll16-staged.
//
// R15 never ran (infra failure: container failed twice). R16 = R15
// resubmitted unchanged. Theory: R14's profile (gemm 48.6us, no pipe >35%
// busy, ~4.8K cyc/tile of convergence/latency bubbles) is an occupancy
// stall at 2 waves/SIMD. Same 256x256 tile and 2-phase schedule, computed
// by 16 WAVES (1024 thr, 4x4 wave grid, 64x64 out/wave): acc drops
// 128->64 AGPR/wave, so 4 waves/SIMD fit the 128-reg unified budget —
// doubling latency absorption. Per-thread staging halves (2 B-gll16 +
// 2 basis stores; chunks {t, 1024+t}).
// All proven invariants kept: 2-phase + mid-tile PACING s_barrier (R11),
// lane-linear LDS writes (R9: conflicts 0), XOR read de-swizzle, tile-local
// k1 for B (R5-R7), x prefetched one tile ahead, silu via gll16 (R13: VGPR
// slack is load-bearing).
//
// d_ws layout (uses 46.7 MB of the 113.7 MB ws):
//   Asilu bf16 [4096][512]   @ 0          ( 4,194,304 B)  silu(x)
//   Bm    bf16 [512][8704]   @ 4194304    ( 8,912,896 B)  Bm = [W | Wb]
//   Cp    bf16 [8][4096][512]@ 13107200   (33,554,432 B)  split-K partials

typedef __bf16 bf16x8 __attribute__((ext_vector_type(8)));
typedef __bf16 bf16x4 __attribute__((ext_vector_type(4)));
typedef float  f32x4  __attribute__((ext_vector_type(4)));

#define KT 8704            // total K = 512*16 + 512
#define SPLITS 8
#define KS (KT / SPLITS)   // 1088 per z-block
#define NT2 (KS / 64)      // 17 K-tiles of BK=64
#define CPE (4096 * 512)   // elements per partial
#define ATILE (256 * 64)   // one tile slot per matrix: 256 rows x 64 k, elems

__device__ __forceinline__ void gll16(const __bf16* g, __bf16* l) {
    __builtin_amdgcn_global_load_lds(
        (const __attribute__((address_space(1))) void*)g,
        (__attribute__((address_space(3))) void*)l, 16, 0, 0);
}

// ---- kernel 1: Asilu = silu(x) (bf16), Bm = [W | Wb] (bf16) ---------------
__global__ void prep_AB(const float* __restrict__ x, const float* __restrict__ W,
                        const float* __restrict__ Wb, __bf16* __restrict__ Asilu,
                        __bf16* __restrict__ B) {
    if (blockIdx.x < 1024) {                     // silu: 8 elems/thread
        int t = blockIdx.x * 256 + threadIdx.x;  // 0 .. 262143
        int e = t * 8;
        float4 v0 = *(const float4*)&x[e];
        float4 v1 = *(const float4*)&x[e + 4];
        float vs[8] = {v0.x, v0.y, v0.z, v0.w, v1.x, v1.y, v1.z, v1.w};
        bf16x8 o;
#pragma unroll
        for (int j = 0; j < 8; ++j) o[j] = (__bf16)(vs[j] / (1.0f + __expf(-vs[j])));
        *(bf16x8*)&Asilu[e] = o;
    } else {                                     // B-part: cast W|Wb, 4 elems/thread
        int t = (blockIdx.x - 1024) * 256 + threadIdx.x;  // 0 .. 512*2176
        int j = t / 2176;
        int c = (t - j * 2176) * 4;
        float4 v;
        if (c < 8192) v = *(const float4*)&W[(size_t)j * 8192 + c];
        else          v = *(const float4*)&Wb[(size_t)j * 512 + (c - 8192)];
        bf16x4 o;
        o[0] = (__bf16)v.x; o[1] = (__bf16)v.y; o[2] = (__bf16)v.z; o[3] = (__bf16)v.w;
        *(bf16x4*)&B[(size_t)j * KT + c] = o;
    }
}

// ---- kernel 2: fused split-K GEMM, 256x256 tile, 16 waves, BK=64, 2-phase -
// Per K-tile u (= R10 schedule, rescaled to 16 waves):
//  P0 (ks=0): 8 ds_read (a0-3, b0-3) | 2 gll16 B(u+1) | if nb: 1 basis
//     store (xA, chunk t) + issue 2 x loads (tile u+2) ; else 2 silu gll16
//     -> setprio 16 MFMA -> s_barrier   (PACING: role-staggers the waves)
//  P1 (ks=1): 8 ds_read | if nb: 1 basis store (xB, chunk 1024+t)
//     -> setprio 16 MFMA -> commit x regs -> __syncthreads
// All staging targets slot^1 (last read in tile u-1's P1, drained by its
// __syncthreads -> WAR-safe). Tile-end __syncthreads publishes basis
// ds_writes and drains the DMA (all issued in P0, >=1 phase old).
//
// LDS chunk layout (R9-proven): per slot, 2048 chunks of 16B; chunk g
// holds source (row = g>>3, src col c = (g&7)^((row>>1)&7)). Reads
// de-swizzle with (q or 4+q)^((r16>>1)&7). ALL writes lane-linear:
// thread t -> chunks t, 1024+t (rows sr, sr+128; same sc since 128>>1
// === 0 mod 8). Zero-conflict (R9-measured pattern).
__global__ __launch_bounds__(1024, 4) void gemm_bt(const float* __restrict__ xg,
                                                   const __bf16* __restrict__ Sg,
                                                   const __bf16* __restrict__ B,
                                                   __bf16* __restrict__ Cp) {
    __shared__ __attribute__((aligned(16))) __bf16 As[2 * ATILE];
    __shared__ __attribute__((aligned(16))) __bf16 Bs[2 * ATILE];

    const int tid  = threadIdx.x;
    const int wave = tid >> 6, lane = tid & 63;
    const int q    = lane >> 4, r16 = lane & 15;
    const int m0 = blockIdx.x * 256, n0 = blockIdx.y * 256, k0 = blockIdx.z * KS;
    const int wm = wave >> 2, wn = wave & 3;     // 4x4 waves; per-wave 64x64 out

    const int sr = tid >> 3;                           // 0..127
    const int sc = (tid & 7) ^ ((tid >> 4) & 7);       // de-swizzled source col
    const __bf16* gB0 = B + (size_t)(n0 + sr) * KT       + k0 + sc * 8;
    const __bf16* gB1 = B + (size_t)(n0 + 128 + sr) * KT + k0 + sc * 8;
    // silu gll16 source (row stride 512; per-tile kk added later; NO k0)
    const __bf16* gS0 = Sg + (size_t)(m0 + sr) * 512       + sc * 8;
    const __bf16* gS1 = Sg + (size_t)(m0 + 128 + sr) * 512 + sc * 8;
    // basis x sources: thread t needs x[m0 + sr + {0,128}][xcol],
    // xcol = (kbase>>4) + (sc>>1); j-half = 8*(sc&1).
    const float* xp0 = xg + (size_t)(m0 + sr) * 512       + (sc >> 1);
    const float* xp1 = xg + (size_t)(m0 + 128 + sr) * 512 + (sc >> 1);
    const float j0f  = (float)(8 * (sc & 1));

    f32x4 acc[4][4] = {};

    // read offsets (XOR de-swizzle, = R9)
    const int swl = (r16 >> 1) & 7;
    const int qx0 = ((q)     ^ swl) * 8;         // ks=0 chunk
    const int qx1 = ((4 + q) ^ swl) * 8;         // ks=1 chunk
    const int aro = (wm * 64 + r16) * 64;
    const int bro = (wn * 64 + r16) * 64;

    // 8 basis values (j = j0..j0+7) for one x value
    auto basis8 = [&](float xv) -> bf16x8 {
        const float zc = 3.75f * xv + 7.5f - j0f;    // z_j = zc - d
        bf16x8 o;
#pragma unroll
        for (int d = 0; d < 8; ++d) { float z = zc - (float)d; o[d] = (__bf16)__expf(-z * z); }
        return o;
    };

    // prologue: B(0) via gll16 (gB* already at k0); A(0) basis (tile 0 is
    // basis for all z: max k0 = 7616 < 8192), lane-linear stores into slot 0.
    // Pre-load x scalars for tile 0's basis staging (tile 1 at (k0+64)>>4).
    float xA, xB;
    {
        const int xo = k0 >> 4;
        float x0 = xp0[xo], x1 = xp1[xo];
        gll16(gB0, &Bs[(size_t)tid * 8]);
        gll16(gB1, &Bs[(size_t)(1024 + tid) * 8]);
        *(bf16x8*)(As + (size_t)tid * 8)          = basis8(x0);
        *(bf16x8*)(As + (size_t)(1024 + tid) * 8) = basis8(x1);
        const int xo1 = (k0 + 64) >> 4;          // always < 512 (k0 max 7616)
        xA = xp0[xo1]; xB = xp1[xo1];
    }
    __syncthreads();

    bf16x8 a[4], b[4];
    for (int u = 0; u < NT2; ++u) {
        const int s   = u & 1;
        const int cbo = s * ATILE;               // compute slot (tile u)
        const int so1 = (s ^ 1) * ATILE;         // staging slot (tile u+1)
        const int k1  = (u + 1) * 64;            // tile-local (gB*: k0 baked in)
        const int kn  = k0 + k1;                 // GLOBAL k-base of tile u+1
        const bool nb = kn < 8192;               // tile u+1 is basis?
        const int kk  = kn - 8192;               // silu col base (when !nb)
        const int k2g = kn + 64;                 // GLOBAL k-base of tile u+2
        const bool nb2 = k2g < 8192;             // tile u+2 is basis?
        float t0, t1;                            // x loads for tile u+2
        // Tail (u+1==NT2): basis z<7 writes a never-consumed tile from valid
        // x cols (<=479); silu z=7 reads <=512 elems past Asilu rows ->
        // lands in Bm (mapped, unused); B reads <=128 B past the slice ->
        // mapped, never consumed.

        // ======== P0: ks=0 (8 ds_read, all DMA, 16 MFMA) ========
#pragma unroll
        for (int mi = 0; mi < 4; ++mi) a[mi] = *(const bf16x8*)(As + cbo + aro + mi * 1024 + qx0);
#pragma unroll
        for (int ni = 0; ni < 4; ++ni) b[ni] = *(const bf16x8*)(Bs + cbo + bro + ni * 1024 + qx0);
        gll16(gB0 + k1, &Bs[(size_t)(so1 + tid * 8)]);
        gll16(gB1 + k1, &Bs[(size_t)(so1 + (1024 + tid) * 8)]);
        if (nb) {                                // basis store pt1 (x from last tile)
            *(bf16x8*)(As + so1 + (size_t)tid * 8) = basis8(xA);
        } else {                                 // silu DMA (z=7)
            gll16(gS0 + kk, &As[(size_t)(so1 + tid * 8)]);
            gll16(gS1 + kk, &As[(size_t)(so1 + (1024 + tid) * 8)]);
        }
        if (nb2) {                               // issue x loads for tile u+2
            const int xo = k2g >> 4;
            t0 = xp0[xo]; t1 = xp1[xo];
        }
        __builtin_amdgcn_s_setprio(1);
#pragma unroll
        for (int mi = 0; mi < 4; ++mi)
#pragma unroll
            for (int ni = 0; ni < 4; ++ni)
                acc[mi][ni] = __builtin_amdgcn_mfma_f32_16x16x32_bf16(a[mi], b[ni], acc[mi][ni], 0, 0, 0);
        __builtin_amdgcn_s_setprio(0);
        __builtin_amdgcn_s_barrier();            // PACING barrier (load-bearing)

        // ======== P1: ks=1 (8 ds_read, basis pt2, 16 MFMA) ========
#pragma unroll
        for (int mi = 0; mi < 4; ++mi) a[mi] = *(const bf16x8*)(As + cbo + aro + mi * 1024 + qx1);
#pragma unroll
        for (int ni = 0; ni < 4; ++ni) b[ni] = *(const bf16x8*)(Bs + cbo + bro + ni * 1024 + qx1);
        if (nb) {                                // basis store pt2
            *(bf16x8*)(As + so1 + (size_t)(1024 + tid) * 8) = basis8(xB);
        }
        __builtin_amdgcn_s_setprio(1);
#pragma unroll
        for (int mi = 0; mi < 4; ++mi)
#pragma unroll
            for (int ni = 0; ni < 4; ++ni)
                acc[mi][ni] = __builtin_amdgcn_mfma_f32_16x16x32_bf16(a[mi], b[ni], acc[mi][ni], 0, 0, 0);
        __builtin_amdgcn_s_setprio(0);
        if (nb2) { xA = t0; xB = t1; }           // commit for tile u+1
        // tile end: publishes basis ds_writes, drains DMA, recycles slots.
        __syncthreads();
    }

    // epilogue: C/D layout col=lane&15, row=(lane>>4)*4+reg; bf16 partials
    __bf16* Cb = Cp + (size_t)blockIdx.z * CPE;
#pragma unroll
    for (int mi = 0; mi < 4; ++mi) {
        const int row = m0 + wm * 64 + mi * 16 + q * 4;
#pragma unroll
        for (int ni = 0; ni < 4; ++ni) {
            const int col = n0 + wn * 64 + ni * 16 + r16;
#pragma unroll
            for (int r = 0; r < 4; ++r)
                Cb[(size_t)(row + r) * 512 + col] = (__bf16)acc[mi][ni][r];
        }
    }
}

// ---- kernel 3: sum 8 bf16 partials + LayerNorm, one wave per row ----------
__global__ void ln_kernel(const __bf16* __restrict__ Cp, const float* __restrict__ gamma,
                          const float* __restrict__ beta, float* __restrict__ out) {
    const int tid  = threadIdx.x;
    const int wave = tid >> 6, lane = tid & 63;
    const int row  = blockIdx.x * 4 + wave;
    const size_t base = (size_t)row * 512 + lane * 8;   // 8 contiguous cols/lane

    float v[8] = {};
    float s = 0.f, s2 = 0.f;
#pragma unroll
    for (int z = 0; z < SPLITS; ++z) {
        bf16x8 p = *(const bf16x8*)(Cp + (size_t)z * CPE + base);
#pragma unroll
        for (int j = 0; j < 8; ++j) v[j] += (float)p[j];
    }
#pragma unroll
    for (int j = 0; j < 8; ++j) { s += v[j]; s2 += v[j] * v[j]; }
#pragma unroll
    for (int m = 32; m >= 1; m >>= 1) {
        s  += __shfl_xor(s, m);
        s2 += __shfl_xor(s2, m);
    }
    const float mean = s * (1.0f / 512.0f);
    const float var  = s2 * (1.0f / 512.0f) - mean * mean;
    const float rs   = rsqrtf(var + 1e-5f);
    float4 o0, o1;
    const float4 g0 = *(const float4*)&gamma[lane * 8];
    const float4 g1 = *(const float4*)&gamma[lane * 8 + 4];
    const float4 b0 = *(const float4*)&beta[lane * 8];
    const float4 b1 = *(const float4*)&beta[lane * 8 + 4];
    o0.x = (v[0] - mean) * rs * g0.x + b0.x;
    o0.y = (v[1] - mean) * rs * g0.y + b0.y;
    o0.z = (v[2] - mean) * rs * g0.z + b0.z;
    o0.w = (v[3] - mean) * rs * g0.w + b0.w;
    o1.x = (v[4] - mean) * rs * g1.x + b1.x;
    o1.y = (v[5] - mean) * rs * g1.y + b1.y;
    o1.z = (v[6] - mean) * rs * g1.z + b1.z;
    o1.w = (v[7] - mean) * rs * g1.w + b1.w;
    *(float4*)&out[base]     = o0;
    *(float4*)&out[base + 4] = o1;
}

extern "C" void kernel_launch(void* const* d_in, const int* in_sizes, int n_in,
                              void* d_out, int out_size, void* d_ws, size_t ws_size,
                              hipStream_t stream) {
    const float* x     = (const float*)d_in[0];
    const float* W     = (const float*)d_in[1];
    const float* Wb    = (const float*)d_in[2];
    const float* gamma = (const float*)d_in[3];
    const float* beta  = (const float*)d_in[4];
    float* out = (float*)d_out;

    char* ws = (char*)d_ws;
    __bf16* Asilu = (__bf16*)ws;                     //  4,194,304 B
    __bf16* Bm    = (__bf16*)(ws + 4194304);         //  8,912,896 B
    __bf16* Cp    = (__bf16*)(ws + 13107200);        // 33,554,432 B

    prep_AB<<<1024 + 4352, 256, 0, stream>>>(x, W, Wb, Asilu, Bm);
    dim3 g(16, 2, SPLITS);
    gemm_bt<<<g, 1024, 0, stream>>>(x, Asilu, Bm, Cp);
    ln_kernel<<<1024, 256, 0, stream>>>(Cp, gamma, beta, out);
}